// Round 3
// baseline (604.097 us; speedup 1.0000x reference)
//
#include <hip/hip_runtime.h>
#include <math.h>

#define DIM 300
#define NN 127
#define KP 320
#define MATSZ (KP*KP)

typedef short bf16x8 __attribute__((ext_vector_type(8)));
typedef float f32x16 __attribute__((ext_vector_type(16)));

__device__ __forceinline__ unsigned short f2bf(float f){
    unsigned u = __float_as_uint(f);
    u += 0x7fffu + ((u >> 16) & 1u);
    return (unsigned short)(u >> 16);
}
__device__ __forceinline__ float sigf(float v){ return 1.0f/(1.0f+__expf(-v)); }
__device__ __forceinline__ float tanh_(float v){
    float t = __expf(-2.0f*fabsf(v));
    float r = (1.0f - t)/(1.0f + t);
    return v < 0.0f ? -r : r;
}
__device__ __forceinline__ void glds16(const void* g, void* l){
    __builtin_amdgcn_global_load_lds(
        (const __attribute__((address_space(1))) unsigned int*)g,
        (__attribute__((address_space(3))) unsigned int*)l, 16, 0, 0);
}

#define MFMA __builtin_amdgcn_mfma_f32_32x32x16_bf16

// ---- one-time: transpose + bf16-convert weights into WT[8][320 n][320 k] ----
// mats 0..2: Wioux i,o,u ; 3..5: Wiouh i,o,u ; 6: Wfx ; 7: Wfh. Pads are 0.
__global__ void prep_weights(const float* __restrict__ Wioux,
                             const float* __restrict__ Wiouh,
                             const float* __restrict__ Wfx,
                             const float* __restrict__ Wfh,
                             unsigned short* __restrict__ WT)
{
    int k = threadIdx.x;     // 0..319
    int n = blockIdx.x;      // 0..319
    int m = blockIdx.y;      // 0..7
    float v = 0.f;
    if (k < DIM && n < DIM){
        if (m < 3)       v = Wioux[k*(3*DIM) + m*DIM + n];
        else if (m < 6)  v = Wiouh[k*(3*DIM) + (m-3)*DIM + n];
        else if (m == 6) v = Wfx[k*DIM + n];
        else             v = Wfh[k*DIM + n];
    }
    WT[m*MATSZ + n*KP + k] = f2bf(v);
}

// ==================== leaf level: nodes 63..126 ====================
// block tile 128 rows x 64 cols; wave (wm,wn): 64 rows x 32 cols, 2 row-tiles.
__global__ __launch_bounds__(256,2)
void leaf_mfma(const float* __restrict__ x,
               const float* __restrict__ bioux, const float* __restrict__ biouh,
               const unsigned short* __restrict__ WT,
               float* __restrict__ H, float* __restrict__ C)
{
    __shared__ __attribute__((aligned(16))) short lds[10240]; // A 4096 + B 3*2048
    const int t = threadIdx.x, lane = t & 63, wave = t >> 6;
    const int wm = wave >> 1, wn = wave & 1;
    const int lrow = lane & 31, half = lane >> 5;
    const int rowBase = blockIdx.x * 128, d0 = blockIdx.y * 64;

    // A staging: 8 chunks of 1KB (16 rows each), 2 per wave
    const float* aptr[2]; int adst[2]; int acg[2];
    #pragma unroll
    for (int i = 0; i < 2; i++){
        int ca = wave*2 + i;
        int r = ca*16 + (lane >> 2);
        int grow = rowBase + r;
        int b = grow >> 6, j = 63 + (grow & 63);
        int cg = (lane & 3) ^ (r & 3);
        aptr[i] = x + (b*NN + j)*DIM + cg*8;
        acg[i] = cg;
        adst[i] = ca*512 + lane*8;
    }
    // B staging: 12 chunks (3 mats x 4 groups), 3 per wave, via global_load_lds
    const unsigned short* bptr[3]; short* bdst[3];
    #pragma unroll
    for (int i = 0; i < 3; i++){
        int cb = wave*3 + i;
        int m = cb >> 2, g = cb & 3;
        int n = g*16 + (lane >> 2);
        int cg = (lane & 3) ^ (n & 3);
        bptr[i] = WT + m*MATSZ + (d0 + n)*KP + cg*8;
        bdst[i] = lds + 4096 + cb*512;
    }

    f32x16 accI[2], accO[2], accU[2];
    #pragma unroll
    for (int rt = 0; rt < 2; rt++)
        #pragma unroll
        for (int q = 0; q < 16; q++){ accI[rt][q]=0.f; accO[rt][q]=0.f; accU[rt][q]=0.f; }

    #pragma unroll
    for (int ks = 0; ks < 10; ks++){
        #pragma unroll
        for (int i = 0; i < 3; i++) glds16(bptr[i] + ks*32, bdst[i]);
        #pragma unroll
        for (int i = 0; i < 2; i++){
            bf16x8 v;
            if ((ks+1)*32 <= DIM){
                float4 p0 = *(const float4*)(aptr[i] + ks*32);
                float4 p1 = *(const float4*)(aptr[i] + ks*32 + 4);
                v[0]=f2bf(p0.x); v[1]=f2bf(p0.y); v[2]=f2bf(p0.z); v[3]=f2bf(p0.w);
                v[4]=f2bf(p1.x); v[5]=f2bf(p1.y); v[6]=f2bf(p1.z); v[7]=f2bf(p1.w);
            } else {
                int kc = ks*32 + acg[i]*8;
                #pragma unroll
                for (int e = 0; e < 8; e++) v[e] = 0;
                if (kc + 8 <= DIM){
                    float4 p0 = *(const float4*)(aptr[i] + ks*32);
                    float4 p1 = *(const float4*)(aptr[i] + ks*32 + 4);
                    v[0]=f2bf(p0.x); v[1]=f2bf(p0.y); v[2]=f2bf(p0.z); v[3]=f2bf(p0.w);
                    v[4]=f2bf(p1.x); v[5]=f2bf(p1.y); v[6]=f2bf(p1.z); v[7]=f2bf(p1.w);
                } else if (kc < DIM){
                    float4 p0 = *(const float4*)(aptr[i] + ks*32);
                    v[0]=f2bf(p0.x); v[1]=f2bf(p0.y); v[2]=f2bf(p0.z); v[3]=f2bf(p0.w);
                }
            }
            *(bf16x8*)(lds + adst[i]) = v;
        }
        __syncthreads();
        #pragma unroll
        for (int kk = 0; kk < 2; kk++){
            int p = ((kk<<1) + half) ^ (lrow & 3);
            const short* Bb = lds + 4096 + (wn*32 + lrow)*32 + p*8;
            bf16x8 b0 = *(const bf16x8*)(Bb);
            bf16x8 b1 = *(const bf16x8*)(Bb + 2048);
            bf16x8 b2 = *(const bf16x8*)(Bb + 4096);
            const short* Ab = lds + (wm*64 + lrow)*32 + p*8;
            #pragma unroll
            for (int rt = 0; rt < 2; rt++){
                bf16x8 ax = *(const bf16x8*)(Ab + rt*1024);
                accI[rt] = MFMA(ax, b0, accI[rt], 0, 0, 0);
                accO[rt] = MFMA(ax, b1, accO[rt], 0, 0, 0);
                accU[rt] = MFMA(ax, b2, accU[rt], 0, 0, 0);
            }
        }
        __syncthreads();
    }
    int d = d0 + wn*32 + lrow;
    if (d < DIM){
        float bi  = bioux[d]       + biouh[d];
        float bo_ = bioux[DIM+d]   + biouh[DIM+d];
        float bu  = bioux[2*DIM+d] + biouh[2*DIM+d];
        #pragma unroll
        for (int rt = 0; rt < 2; rt++)
            #pragma unroll
            for (int q = 0; q < 16; q++){
                int grow = rowBase + wm*64 + rt*32 + (q&3) + 8*(q>>2) + 4*half;
                int b = grow >> 6, j = 63 + (grow & 63);
                int ob = (b*NN + j)*DIM + d;
                float iv = sigf (accI[rt][q] + bi);
                float ov = sigf (accO[rt][q] + bo_);
                float uv = tanh_(accU[rt][q] + bu);
                float cv = iv*uv;
                C[ob] = cv;
                H[ob] = ov*tanh_(cv);
            }
    }
}

// ==================== internal levels ====================
__global__ __launch_bounds__(256,2)
void level_mfma(const float* __restrict__ x,
                const float* __restrict__ bioux, const float* __restrict__ biouh,
                const float* __restrict__ bfx,   const float* __restrict__ bfh,
                const unsigned short* __restrict__ WT,
                float* __restrict__ H, float* __restrict__ C,
                int lo, int lshift)
{
    __shared__ __attribute__((aligned(16))) short lds[28672]; // A 3*4096 + B 8*2048
    const int t = threadIdx.x, lane = t & 63, wave = t >> 6;
    const int wm = wave >> 1, wn = wave & 1;
    const int lrow = lane & 31, half = lane >> 5;
    const int rowBase = blockIdx.x * 128, d0 = blockIdx.y * 64;
    const int nmask = (1 << lshift) - 1;

    // A staging: 24 chunks (3 streams x 8 row-groups), 6 per wave
    const float* aptr[6]; int adst[6]; int acg[6];
    #pragma unroll
    for (int i = 0; i < 6; i++){
        int ca = wave*6 + i;
        int s = ca >> 3, rg = ca & 7;
        int r = rg*16 + (lane >> 2);
        int grow = rowBase + r;
        int b = grow >> lshift, j = lo + (grow & nmask);
        int node = (s == 0) ? j : ((s == 1) ? 2*j+1 : 2*j+2);
        const float* base = (s == 0) ? x : H;
        int cg = (lane & 3) ^ (r & 3);
        aptr[i] = base + (b*NN + node)*DIM + cg*8;
        acg[i] = cg;
        adst[i] = ca*512 + lane*8;
    }
    // B staging: 32 chunks (8 mats x 4 groups), 8 per wave
    const unsigned short* bptr[8]; short* bdst[8];
    #pragma unroll
    for (int i = 0; i < 8; i++){
        int cb = wave*8 + i;
        int m = cb >> 2, g = cb & 3;
        int n = g*16 + (lane >> 2);
        int cg = (lane & 3) ^ (n & 3);
        bptr[i] = WT + m*MATSZ + (d0 + n)*KP + cg*8;
        bdst[i] = lds + 12288 + cb*512;
    }

    f32x16 accI[2], accO[2], accU[2], accF0[2], accF1[2];
    #pragma unroll
    for (int rt = 0; rt < 2; rt++)
        #pragma unroll
        for (int q = 0; q < 16; q++){
            accI[rt][q]=0.f; accO[rt][q]=0.f; accU[rt][q]=0.f;
            accF0[rt][q]=0.f; accF1[rt][q]=0.f;
        }

    #pragma unroll
    for (int ks = 0; ks < 10; ks++){
        #pragma unroll
        for (int i = 0; i < 8; i++) glds16(bptr[i] + ks*32, bdst[i]);
        #pragma unroll
        for (int i = 0; i < 6; i++){
            bf16x8 v;
            if ((ks+1)*32 <= DIM){
                float4 p0 = *(const float4*)(aptr[i] + ks*32);
                float4 p1 = *(const float4*)(aptr[i] + ks*32 + 4);
                v[0]=f2bf(p0.x); v[1]=f2bf(p0.y); v[2]=f2bf(p0.z); v[3]=f2bf(p0.w);
                v[4]=f2bf(p1.x); v[5]=f2bf(p1.y); v[6]=f2bf(p1.z); v[7]=f2bf(p1.w);
            } else {
                int kc = ks*32 + acg[i]*8;
                #pragma unroll
                for (int e = 0; e < 8; e++) v[e] = 0;
                if (kc + 8 <= DIM){
                    float4 p0 = *(const float4*)(aptr[i] + ks*32);
                    float4 p1 = *(const float4*)(aptr[i] + ks*32 + 4);
                    v[0]=f2bf(p0.x); v[1]=f2bf(p0.y); v[2]=f2bf(p0.z); v[3]=f2bf(p0.w);
                    v[4]=f2bf(p1.x); v[5]=f2bf(p1.y); v[6]=f2bf(p1.z); v[7]=f2bf(p1.w);
                } else if (kc < DIM){
                    float4 p0 = *(const float4*)(aptr[i] + ks*32);
                    v[0]=f2bf(p0.x); v[1]=f2bf(p0.y); v[2]=f2bf(p0.z); v[3]=f2bf(p0.w);
                }
            }
            *(bf16x8*)(lds + adst[i]) = v;
        }
        __syncthreads();
        #pragma unroll
        for (int kk = 0; kk < 2; kk++){
            int p = ((kk<<1) + half) ^ (lrow & 3);
            const short* Bb = lds + 12288 + (wn*32 + lrow)*32 + p*8;
            bf16x8 b0 = *(const bf16x8*)(Bb);
            bf16x8 b1 = *(const bf16x8*)(Bb + 2048);
            bf16x8 b2 = *(const bf16x8*)(Bb + 2*2048);
            bf16x8 b3 = *(const bf16x8*)(Bb + 3*2048);
            bf16x8 b4 = *(const bf16x8*)(Bb + 4*2048);
            bf16x8 b5 = *(const bf16x8*)(Bb + 5*2048);
            bf16x8 b6 = *(const bf16x8*)(Bb + 6*2048);
            bf16x8 b7 = *(const bf16x8*)(Bb + 7*2048);
            const short* Ab = lds + (wm*64 + lrow)*32 + p*8;
            #pragma unroll
            for (int rt = 0; rt < 2; rt++){
                bf16x8 ax = *(const bf16x8*)(Ab + rt*1024);
                bf16x8 a0 = *(const bf16x8*)(Ab + 4096 + rt*1024);
                bf16x8 a1 = *(const bf16x8*)(Ab + 8192 + rt*1024);
                accI[rt]  = MFMA(ax, b0, accI[rt], 0, 0, 0);
                accI[rt]  = MFMA(a0, b3, accI[rt], 0, 0, 0);
                accI[rt]  = MFMA(a1, b3, accI[rt], 0, 0, 0);
                accO[rt]  = MFMA(ax, b1, accO[rt], 0, 0, 0);
                accO[rt]  = MFMA(a0, b4, accO[rt], 0, 0, 0);
                accO[rt]  = MFMA(a1, b4, accO[rt], 0, 0, 0);
                accU[rt]  = MFMA(ax, b2, accU[rt], 0, 0, 0);
                accU[rt]  = MFMA(a0, b5, accU[rt], 0, 0, 0);
                accU[rt]  = MFMA(a1, b5, accU[rt], 0, 0, 0);
                accF0[rt] = MFMA(ax, b6, accF0[rt], 0, 0, 0);
                accF0[rt] = MFMA(a0, b7, accF0[rt], 0, 0, 0);
                accF1[rt] = MFMA(ax, b6, accF1[rt], 0, 0, 0);
                accF1[rt] = MFMA(a1, b7, accF1[rt], 0, 0, 0);
            }
        }
        __syncthreads();
    }
    int d = d0 + wn*32 + lrow;
    if (d < DIM){
        float bi  = bioux[d]       + biouh[d];
        float bo_ = bioux[DIM+d]   + biouh[DIM+d];
        float bu  = bioux[2*DIM+d] + biouh[2*DIM+d];
        float bf_ = bfx[d] + bfh[d];
        #pragma unroll
        for (int rt = 0; rt < 2; rt++)
            #pragma unroll
            for (int q = 0; q < 16; q++){
                int grow = rowBase + wm*64 + rt*32 + (q&3) + 8*(q>>2) + 4*half;
                int b = grow >> lshift, j = lo + (grow & nmask);
                int ob  = (b*NN + j)*DIM + d;
                float c0 = C[(b*NN + 2*j+1)*DIM + d];
                float c1 = C[(b*NN + 2*j+2)*DIM + d];
                float iv = sigf (accI[rt][q] + bi);
                float ov = sigf (accO[rt][q] + bo_);
                float uv = tanh_(accU[rt][q] + bu);
                float f0 = sigf (accF0[rt][q] + bf_);
                float f1 = sigf (accF1[rt][q] + bf_);
                float cv = iv*uv + f0*c0 + f1*c1;
                C[ob] = cv;
                H[ob] = ov*tanh_(cv);
            }
    }
}

extern "C" void kernel_launch(void* const* d_in, const int* in_sizes, int n_in,
                              void* d_out, int out_size, void* d_ws, size_t ws_size,
                              hipStream_t stream) {
    const float* x     = (const float*)d_in[0];
    const float* Wioux = (const float*)d_in[1];
    const float* bioux = (const float*)d_in[2];
    const float* Wiouh = (const float*)d_in[3];
    const float* biouh = (const float*)d_in[4];
    const float* Wfx   = (const float*)d_in[5];
    const float* bfx   = (const float*)d_in[6];
    const float* Wfh   = (const float*)d_in[7];
    const float* bfh   = (const float*)d_in[8];
    float* H = (float*)d_out;
    float* C = (float*)d_ws;                                        // 78,028,800 B
    unsigned short* WT = (unsigned short*)((char*)d_ws + 78028800); // 1,638,400 B

    prep_weights<<<dim3(KP, 8), KP, 0, stream>>>(Wioux, Wiouh, Wfx, Wfh, WT);
    // leaves: 32768 rows -> 256 x 5 blocks
    leaf_mfma<<<dim3(256, 5), 256, 0, stream>>>(x, bioux, biouh, WT, H, C);
    // internal levels deepest-first: rows = 512<<l -> (4<<l) x 5 blocks
    for (int l = 5; l >= 0; l--){
        level_mfma<<<dim3(4 << l, 5), 256, 0, stream>>>(
            x, bioux, biouh, bfx, bfh, WT, H, C, (1 << l) - 1, l);
    }
}